// Round 1
// baseline (80.379 us; speedup 1.0000x reference)
//
#include <hip/hip_runtime.h>
#include <hip/hip_bf16.h>
#include <stdint.h>

typedef __bf16 bf16x8 __attribute__((ext_vector_type(8)));
typedef float  f32x4  __attribute__((ext_vector_type(4)));

#define N_EMBED   2048
#define N_EXP     64
#define KCHUNK    64
#define NKC       (N_EMBED / KCHUNK)   // 32
#define TILEB     16384                // bytes per k-chunk image (hi 8KB + lo 8KB)

// ---------------------------------------------------------------------------
// Prelude: W [64][2048] fp32 -> pre-swizzled bf16 hi/lo image in ws.
// Folds the 0.5 = (alpha-1)/temperature scale into W.
// Image: for kc in [0,32): at kc*16384:
//   [0,8192)    : hi tile, element (e,dd) at byte ((e*128 + dd*2) ^ ((e&7)<<4))
//   [8192,16384): lo tile, same layout
// ---------------------------------------------------------------------------
__global__ __launch_bounds__(256) void convert_w_kernel(
        const float* __restrict__ W, uint8_t* __restrict__ wsimg) {
    int tid = blockIdx.x * 256 + threadIdx.x;   // 16384 threads total
    int e   = tid >> 8;                          // expert 0..63
    int d0  = (tid & 255) * 8;                   // 8 consecutive d
    int kc  = d0 >> 6;
    int dd0 = d0 & 63;
    const float* src = W + e * N_EMBED + d0;
    float4 f0 = *(const float4*)(src);
    float4 f1 = *(const float4*)(src + 4);
    float v[8] = {f0.x, f0.y, f0.z, f0.w, f1.x, f1.y, f1.z, f1.w};
    union { __bf16 h[8]; uint4 u; } hi, lo;
#pragma unroll
    for (int j = 0; j < 8; ++j) {
        float s = 0.5f * v[j];
        __bf16 h = (__bf16)s;
        hi.h[j] = h;
        lo.h[j] = (__bf16)(s - (float)h);
    }
    uint32_t off = (uint32_t)((e * 128 + dd0 * 2) ^ ((e & 7) << 4));
    uint8_t* base = wsimg + (size_t)kc * TILEB + off;
    *(uint4*)(base)        = hi.u;
    *(uint4*)(base + 8192) = lo.u;
}

// ---------------------------------------------------------------------------
// Main fused kernel: GEMM (split-bf16 MFMA) + entmax-1.5 bisection epilogue.
// 4 waves/block, 16 token-rows per wave, all 64 experts per wave.
// ---------------------------------------------------------------------------
__device__ inline void split8(const float4& p, const float4& q,
                              bf16x8& h8, bf16x8& l8) {
    float v[8] = {p.x, p.y, p.z, p.w, q.x, q.y, q.z, q.w};
#pragma unroll
    for (int j = 0; j < 8; ++j) {
        __bf16 h = (__bf16)v[j];
        h8[j] = h;
        l8[j] = (__bf16)(v[j] - (float)h);
    }
}

__global__ __launch_bounds__(256, 2) void router_kernel(
        const float* __restrict__ x, const uint8_t* __restrict__ wsimg,
        const float* __restrict__ bias, float* __restrict__ out) {
    __shared__ uint8_t lds[TILEB];

    const int tid  = threadIdx.x;
    const int wave = tid >> 6;
    const int lane = tid & 63;
    const int l15  = lane & 15;
    const int l4   = lane >> 4;
    const int rowbase = blockIdx.x * 64 + wave * 16;
    const float* xrow = x + (size_t)(rowbase + l15) * N_EMBED;

    f32x4 acc[4];
#pragma unroll
    for (int t = 0; t < 4; ++t) acc[t] = (f32x4){0.f, 0.f, 0.f, 0.f};

    // LDS byte offsets of B fragments (hi half): tile t, k-step s
    uint32_t boff[4][2];
#pragma unroll
    for (int t = 0; t < 4; ++t)
#pragma unroll
        for (int s = 0; s < 2; ++s)
            boff[t][s] = (uint32_t)(((16 * t + l15) * 128 + s * 64 + l4 * 16)
                                    ^ ((l15 & 7) << 4));

#pragma unroll 1
    for (int kc = 0; kc < NKC; ++kc) {
        // stage W k-chunk into LDS (linear dest; source image is pre-swizzled)
        const uint8_t* gsrc = wsimg + (size_t)kc * TILEB;
#pragma unroll
        for (int j = 0; j < 4; ++j) {
            __builtin_amdgcn_global_load_lds(
                (const __attribute__((address_space(1))) void*)(gsrc + j * 4096 + tid * 16),
                (__attribute__((address_space(3))) void*)(lds + j * 4096 + tid * 16),
                16, 0, 0);
        }
        // A: 16 fp32 of this token row for this k-chunk
        const float* ap = xrow + kc * KCHUNK + l4 * 8;
        float4 a0 = *(const float4*)(ap);
        float4 a1 = *(const float4*)(ap + 4);
        float4 a2 = *(const float4*)(ap + 32);
        float4 a3 = *(const float4*)(ap + 36);

        __syncthreads();   // drains vmcnt: B in LDS, A in regs

        bf16x8 ahi0, alo0, ahi1, alo1;
        split8(a0, a1, ahi0, alo0);
        split8(a2, a3, ahi1, alo1);

#pragma unroll
        for (int s = 0; s < 2; ++s) {
            bf16x8 ah = s ? ahi1 : ahi0;
            bf16x8 al = s ? alo1 : alo0;
#pragma unroll
            for (int t = 0; t < 4; ++t) {
                bf16x8 bh = *(const bf16x8*)(lds + boff[t][s]);
                bf16x8 bl = *(const bf16x8*)(lds + 8192 + boff[t][s]);
                acc[t] = __builtin_amdgcn_mfma_f32_16x16x32_bf16(ah, bh, acc[t], 0, 0, 0);
                acc[t] = __builtin_amdgcn_mfma_f32_16x16x32_bf16(al, bh, acc[t], 0, 0, 0);
                acc[t] = __builtin_amdgcn_mfma_f32_16x16x32_bf16(ah, bl, acc[t], 0, 0, 0);
            }
        }
        __syncthreads();   // all waves done reading LDS before next overwrite
    }

    // ---------------- entmax-1.5 epilogue ----------------
    // C layout: expert e = t*16 + l15, token row = rowbase + l4*4 + reg.
    // Each token row lives in one 16-lane group (fixed l4) -> shfl_xor {1,2,4,8}.
    float bv0 = 0.5f * bias[l15];
    float bv1 = 0.5f * bias[16 + l15];
    float bv2 = 0.5f * bias[32 + l15];
    float bv3 = 0.5f * bias[48 + l15];

#pragma unroll
    for (int r = 0; r < 4; ++r) {
        float v0 = acc[0][r] + bv0;
        float v1 = acc[1][r] + bv1;
        float v2 = acc[2][r] + bv2;
        float v3 = acc[3][r] + bv3;

        float m = fmaxf(fmaxf(v0, v1), fmaxf(v2, v3));
        m = fmaxf(m, __shfl_xor(m, 1, 64));
        m = fmaxf(m, __shfl_xor(m, 2, 64));
        m = fmaxf(m, __shfl_xor(m, 4, 64));
        m = fmaxf(m, __shfl_xor(m, 8, 64));

        float tau_lo = m - 1.0f;
        float tau_hi = m - 0.000244140625f;   // (1/64)^(1/(alpha-1)) = (1/64)^2
        float dm = tau_hi - tau_lo;

        float d0 = fmaxf(v0 - tau_lo, 0.f), d1 = fmaxf(v1 - tau_lo, 0.f);
        float d2 = fmaxf(v2 - tau_lo, 0.f), d3 = fmaxf(v3 - tau_lo, 0.f);
        float s0 = d0 * d0; s0 = fmaf(d1, d1, s0); s0 = fmaf(d2, d2, s0); s0 = fmaf(d3, d3, s0);
        s0 += __shfl_xor(s0, 1, 64);
        s0 += __shfl_xor(s0, 2, 64);
        s0 += __shfl_xor(s0, 4, 64);
        s0 += __shfl_xor(s0, 8, 64);
        const float f_lo = s0 - 1.0f;   // fixed for all iterations (as in reference)

        float tau_m = tau_lo, fsum = 1.0f;
#pragma unroll 1
        for (int it = 0; it < 25; ++it) {
            dm *= 0.5f;
            tau_m = tau_lo + dm;
            float e0 = fmaxf(v0 - tau_m, 0.f), e1 = fmaxf(v1 - tau_m, 0.f);
            float e2 = fmaxf(v2 - tau_m, 0.f), e3 = fmaxf(v3 - tau_m, 0.f);
            float s = e0 * e0; s = fmaf(e1, e1, s); s = fmaf(e2, e2, s); s = fmaf(e3, e3, s);
            s += __shfl_xor(s, 1, 64);
            s += __shfl_xor(s, 2, 64);
            s += __shfl_xor(s, 4, 64);
            s += __shfl_xor(s, 8, 64);
            if ((s - 1.0f) * f_lo >= 0.0f) tau_lo = tau_m;
            fsum = s;
        }
        // p at last midpoint, renormalized by its own sum (ensure_sum_one)
        float rinv = 1.0f / fsum;
        float p0 = fmaxf(v0 - tau_m, 0.f); p0 = p0 * p0 * rinv;
        float p1 = fmaxf(v1 - tau_m, 0.f); p1 = p1 * p1 * rinv;
        float p2 = fmaxf(v2 - tau_m, 0.f); p2 = p2 * p2 * rinv;
        float p3 = fmaxf(v3 - tau_m, 0.f); p3 = p3 * p3 * rinv;

        int trow = rowbase + l4 * 4 + r;
        float* op = out + (size_t)trow * N_EXP + l15;
        op[0]  = p0;
        op[16] = p1;
        op[32] = p2;
        op[48] = p3;
    }
}

// ---------------------------------------------------------------------------
extern "C" void kernel_launch(void* const* d_in, const int* in_sizes, int n_in,
                              void* d_out, int out_size, void* d_ws, size_t ws_size,
                              hipStream_t stream) {
    (void)n_in; (void)out_size; (void)ws_size;
    const float* x  = (const float*)d_in[0];   // [T, 2048]
    const float* W  = (const float*)d_in[1];   // [64, 2048]
    const float* b  = (const float*)d_in[2];   // [64]
    float* out      = (float*)d_out;           // [T, 64]
    uint8_t* wsimg  = (uint8_t*)d_ws;          // 512 KB W image

    const int T = in_sizes[0] / N_EMBED;       // 32768

    convert_w_kernel<<<dim3(64), dim3(256), 0, stream>>>(W, wsimg);
    router_kernel<<<dim3(T / 64), dim3(256), 0, stream>>>(x, wsimg, b, out);
}